// Round 12
// baseline (492.611 us; speedup 1.0000x reference)
//
#include <hip/hip_runtime.h>
#include <hip/hip_bf16.h>
#include <stdint.h>

#define CDIM 192
#define KDIM 960
#define HW   65536
#define WI   256

// workspace: Wb bf16 (368640 B) + bias f32 (768 B)
#define OFF_BIAS 368640u
#define NEED_WS  369408u

// fused-kernel LDS geometry (R4-proven): x slices TRANSPOSED [px_local:132][c:32] bf16,
// row stride 80 B; W double-buffer 2 * 12288 B.  Total 56256 B -> 2 blocks/CU.
#define ROW_B    80
#define SLICE_B  10560   // 132 * 80
#define WOFF     31680   // 3 * SLICE_B
#define WBUF     12288

typedef __attribute__((ext_vector_type(8))) short short8;
typedef __attribute__((ext_vector_type(16))) float floatx16;

__device__ __forceinline__ uint16_t f2b(float v) {
    __hip_bfloat16 h = __float2bfloat16(v);
    return *reinterpret_cast<uint16_t*>(&h);
}

// inline dtype detect: all blocks sample the SAME 256 strided dwords of x -> identical flag.
__device__ __forceinline__ int detect_f(const void* xsrc) {
    const uint32_t* xw = (const uint32_t*)xsrc;
    uint32_t d = xw[(size_t)threadIdx.x * 98083u];   // max 255*98083 < 25,165,824 (bf16 dwords)
    uint32_t e = (d >> 7) & 0xFF;
    int isb = (e >= 110 && e <= 130) ? 1 : 0;
    return (__syncthreads_count(isb) >= 128) ? 1 : 0;
}

// ---------------- prep: canonicalize W -> bf16, bias -> f32 (detect inline) -------------------
__global__ __launch_bounds__(256) void prep_kernel(const void* __restrict__ Wsrc,
                                                   const void* __restrict__ bsrc,
                                                   const void* __restrict__ xsrc,
                                                   __hip_bfloat16* __restrict__ Wb,
                                                   float* __restrict__ bfp) {
    const int f = detect_f(xsrc);
    if (blockIdx.x < 720) {
        int i = blockIdx.x * 256 + threadIdx.x;        // < 184320
        float v = f ? __bfloat162float(((const __hip_bfloat16*)Wsrc)[i])
                    : ((const float*)Wsrc)[i];
        Wb[i] = __float2bfloat16(v);
    } else if (threadIdx.x < CDIM) {
        int j = threadIdx.x;
        bfp[j] = f ? __bfloat162float(((const __hip_bfloat16*)bsrc)[j])
                   : ((const float*)bsrc)[j];
    }
}

// ---------------- fused transpose-stage + GEMM + bias: 32x32x16 MFMA variant -------------------
// Identical skeleton to the R4/R11 kernel (same STAGE, W-dbuf, barriers, vmcnt(3));
// only the MFMA shape changes: 12 x mfma_f32_32x32x16_bf16 per step (was 24 x 16x16x32).
// A: row=lane&31, k=(lane>>5)*8+i.  B: col=lane&31, same k split.
// C/D: col=lane&31, row=(reg&3)+8*(reg>>2)+4*(lane>>5), reg 0..15.
__device__ __forceinline__ void gload16(const void* g, void* l) {
    __builtin_amdgcn_global_load_lds(
        (const __attribute__((address_space(1))) uint32_t*)g,
        (__attribute__((address_space(3))) uint32_t*)l, 16, 0, 0);
}

__global__ __launch_bounds__(256, 2) void fused_kernel(const void* __restrict__ xsrc,
                                                       const __hip_bfloat16* __restrict__ Wm,
                                                       const float* __restrict__ biasf,
                                                       void* __restrict__ outv) {
    __shared__ char lds[WOFF + 2 * WBUF];   // 56256 B -> 2 blocks/CU
    char* xsl  = lds;
    char* ldsW = lds + WOFF;
    const int tid  = threadIdx.x;
    const int lane = tid & 63, wave = tid >> 6;
    const int l31  = lane & 31, hi32 = lane >> 5;

    const int f = detect_f(xsrc);

    // XCD-aware bijective swizzle: consecutive wg -> h-adjacent, L2-local halo reuse
    const int nwg  = (int)gridDim.x;                 // 2048, % 8 == 0
    const int bid0 = (int)blockIdx.x;
    const int wg   = (bid0 & 7) * (nwg >> 3) + (bid0 >> 3);

    const int bb = wg >> 9;                          // plane 0..3
    const int r  = wg & 511;
    const int h  = r >> 1;
    const int w0 = (r & 1) << 7;
    const int p0 = h * WI + w0;
    const int obase = (wave >> 1) * 96;              // o-half per wave-pair (3 x 32)
    const int nbase = (wave & 1) * 64;               // px-half (2 x 32)

    // W staging pointers (R4 layout: LDS [kq8:4][o:192] 16B chunks per 32-c step)
    const char* gw[3];
    int ldsoff[3];
    #pragma unroll
    for (int t = 0; t < 3; ++t) {
        int chunk = tid + t * 256;
        int kq = chunk / 192, o = chunk % 192;
        gw[t] = (const char*)Wm + ((size_t)o * KDIM + kq * 8) * 2;
        ldsoff[t] = chunk * 16;
    }
    // A-frag offsets: [mt][q] -> ((q*2 + hi32)*192 + obase + mt*32 + l31) * 16
    int aoff[3][2];
    #pragma unroll
    for (int mt = 0; mt < 3; ++mt)
        #pragma unroll
        for (int q = 0; q < 2; ++q)
            aoff[mt][q] = ((q * 2 + hi32) * 192 + obase + mt * 32 + l31) * 16;

    // B-fragment geometry: pl = local out-col 0..127 (2 tiles of 32)
    int pxa[2]; bool w255[2], wzero[2];
    #pragma unroll
    for (int nt = 0; nt < 2; ++nt) {
        int pl = nbase + nt * 32 + l31;
        pxa[nt]   = (pl + 1) * ROW_B;                // px_local = pl+1 (center)
        w255[nt]  = ((w0 + pl) == 255);
        wzero[nt] = ((w0 + pl) == 0);
    }

    // staging geometry: main threads cover px_local 1..128 x 16 c each
    const int scc  = tid >> 7;                       // c-half 0/1
    const int spx  = (tid & 127) + 1;                // px_local 1..128
    const int scol = w0 + (tid & 127);               // global col, always 0..255
    // edge threads (tid<64) cover px_local 0 (col w0-1) and 129 (col w0+128)
    const int ec = tid >> 1, ee = tid & 1;
    int ecol = ee ? (w0 + 128) : (w0 - 1);
    if (ecol < 0) ecol = 0;
    if (ecol > 255) ecol = 255;                      // clamped cols are killed at consume
    const int epx = ee ? 129 : 0;

    const size_t esz = f ? 2u : 4u;
    const char* xp = (const char*)xsrc + (size_t)bb * CDIM * HW * esz;

    int hr[3];
    #pragma unroll
    for (int rr = 0; rr < 3; ++rr) {
        int v = h - 1 + rr;
        hr[rr] = v < 0 ? 0 : (v > 255 ? 255 : v);    // clamped rows are killed at consume
    }

    floatx16 acc[3][2];
    #pragma unroll
    for (int mt = 0; mt < 3; ++mt)
        #pragma unroll
        for (int nt = 0; nt < 2; ++nt)
            #pragma unroll
            for (int rr = 0; rr < 16; ++rr)
                acc[mt][nt][rr] = 0.f;

#define STAGE(JJ)                                                                          \
    {                                                                                      \
        const int c0 = (JJ) * 32;                                                          \
        _Pragma("unroll")                                                                  \
        for (int rr = 0; rr < 3; ++rr) {                                                   \
            uint32_t tmp[16];                                                              \
            const size_t rowoff = (size_t)hr[rr] * WI;                                     \
            if (f) {                                                                       \
                const uint16_t* xg = (const uint16_t*)xp;                                  \
                _Pragma("unroll")                                                          \
                for (int cc = 0; cc < 16; ++cc)                                            \
                    tmp[cc] = xg[(size_t)(c0 + scc * 16 + cc) * HW + rowoff + scol];       \
            } else {                                                                       \
                const float* xg = (const float*)xp;                                        \
                _Pragma("unroll")                                                          \
                for (int cc = 0; cc < 16; ++cc)                                            \
                    tmp[cc] = f2b(xg[(size_t)(c0 + scc * 16 + cc) * HW + rowoff + scol]);  \
            }                                                                              \
            uint4 q0, q1;                                                                  \
            q0.x = tmp[0] | (tmp[1] << 16);  q0.y = tmp[2] | (tmp[3] << 16);               \
            q0.z = tmp[4] | (tmp[5] << 16);  q0.w = tmp[6] | (tmp[7] << 16);               \
            q1.x = tmp[8] | (tmp[9] << 16);  q1.y = tmp[10] | (tmp[11] << 16);             \
            q1.z = tmp[12] | (tmp[13] << 16); q1.w = tmp[14] | (tmp[15] << 16);            \
            char* base = xsl + rr * SLICE_B + spx * ROW_B + scc * 32;                      \
            *(uint4*)(base)      = q0;                                                     \
            *(uint4*)(base + 16) = q1;                                                     \
        }                                                                                  \
        if (tid < 64) {                                                                    \
            _Pragma("unroll")                                                              \
            for (int rr = 0; rr < 3; ++rr) {                                               \
                const size_t gi = (size_t)(c0 + ec) * HW + (size_t)hr[rr] * WI + ecol;     \
                uint16_t v = f ? ((const uint16_t*)xp)[gi]                                 \
                               : f2b(((const float*)xp)[gi]);                              \
                *(uint16_t*)(xsl + rr * SLICE_B + epx * ROW_B + ec * 2) = v;               \
            }                                                                              \
        }                                                                                  \
    }

    // prologue: W(j=0,s=0) gload (oldest), then stage j=0, then full sync
    #pragma unroll
    for (int t = 0; t < 3; ++t) gload16(gw[t], ldsW + ldsoff[t]);
    STAGE(0)
    __syncthreads();

    for (int j = 0; j < 6; ++j) {
        #pragma unroll
        for (int s = 0; s < 5; ++s) {
            const int cur = (s & 1) * WBUF;
            __builtin_amdgcn_s_barrier();           // prev step's LDS reads done everywhere
            __builtin_amdgcn_sched_barrier(0);
            if (s < 4) {
                const int nxt = WBUF - cur;
                #pragma unroll
                for (int t = 0; t < 3; ++t)
                    gload16(gw[t] + (size_t)((s + 1) * 6 + j) * 64, ldsW + nxt + ldsoff[t]);
            }
            __builtin_amdgcn_sched_barrier(0);
            if (s < 4) asm volatile("s_waitcnt vmcnt(3)" ::: "memory");  // W(j,s) landed
            else       asm volatile("s_waitcnt vmcnt(0)" ::: "memory");
            __builtin_amdgcn_sched_barrier(0);
            __builtin_amdgcn_s_barrier();           // W(j,s) visible to all waves
            __builtin_amdgcn_sched_barrier(0);

            // A-frags: [mt][q], 16B each from W LDS
            short8 af[3][2];
            #pragma unroll
            for (int mt = 0; mt < 3; ++mt)
                #pragma unroll
                for (int q = 0; q < 2; ++q)
                    af[mt][q] = *(const short8*)(ldsW + cur + aoff[mt][q]);

            // B-frags from LDS x-slices: slice/col-shift per s; k-offset q*32 + hi32*16 bytes
            const int so   = (s == 3) ? 2 * SLICE_B : (s == 4) ? 0 : SLICE_B;
            const int dw80 = (s == 1) ? ROW_B : (s == 2) ? -ROW_B : 0;
            const bool skip = (s == 3 && h == 255) || (s == 4 && h == 0);
            short8 bf[2][2];
            #pragma unroll
            for (int nt = 0; nt < 2; ++nt) {
                const bool kill = skip || (s == 1 && w255[nt]) || (s == 2 && wzero[nt]);
                #pragma unroll
                for (int q = 0; q < 2; ++q) {
                    short8 v = *(const short8*)(xsl + so + pxa[nt] + dw80
                                                + q * 32 + hi32 * 16);
                    bf[nt][q] = kill ? (short8){0, 0, 0, 0, 0, 0, 0, 0} : v;
                }
            }

            __builtin_amdgcn_s_setprio(1);
            #pragma unroll
            for (int q = 0; q < 2; ++q)
                #pragma unroll
                for (int mt = 0; mt < 3; ++mt)
                    #pragma unroll
                    for (int nt = 0; nt < 2; ++nt)
                        acc[mt][nt] = __builtin_amdgcn_mfma_f32_32x32x16_bf16(
                            af[mt][q], bf[nt][q], acc[mt][nt], 0, 0, 0);
            __builtin_amdgcn_s_setprio(0);
        }
        if (j < 5) {
            __syncthreads();                        // all reads of xs[j] and Wbuf done
            #pragma unroll
            for (int t = 0; t < 3; ++t)             // W(j+1, s=0) -> buf0
                gload16(gw[t] + (size_t)(j + 1) * 64, ldsW + ldsoff[t]);
            STAGE(j + 1)
            __syncthreads();                        // xs[j+1] (and W) visible
        }
    }

    // epilogue: + bias; D layout: col(px)=lane&31, row(o)=(reg&3)+8*(reg>>2)+4*hi32
    #pragma unroll
    for (int mt = 0; mt < 3; ++mt) {
        #pragma unroll
        for (int reg = 0; reg < 16; ++reg) {
            const int row = (reg & 3) + 8 * (reg >> 2) + 4 * hi32;
            const int o   = obase + mt * 32 + row;
            const float bv = biasf[o];
            #pragma unroll
            for (int nt = 0; nt < 2; ++nt) {
                const int px = nbase + nt * 32 + l31;
                const size_t idx = ((size_t)(bb * CDIM + o) * HW) + p0 + px;
                if (f) ((__hip_bfloat16*)outv)[idx] = __float2bfloat16(acc[mt][nt][reg] + bv);
                else   ((float*)outv)[idx]          = acc[mt][nt][reg] + bv;
            }
        }
    }
#undef STAGE
}

// ---------------- fallback: naive direct conv, inline detect, no workspace ---------------------
__global__ __launch_bounds__(256) void fallback_kernel(const void* __restrict__ xv,
                                                       const void* __restrict__ Wv,
                                                       const void* __restrict__ bv,
                                                       void* __restrict__ outv) {
    __shared__ float Wl[KDIM];
    const int f = detect_f(xv);
    const int tid = threadIdx.x;
    const int bid = blockIdx.x;
    const int h = bid & 255;
    const int bo = bid >> 8;
    const int o = bo % CDIM;
    const int b = bo / CDIM;
    if (f) {
        const __hip_bfloat16* W16 = (const __hip_bfloat16*)Wv;
        for (int i = tid; i < KDIM; i += 256) Wl[i] = __bfloat162float(W16[(size_t)o * KDIM + i]);
    } else {
        const float* W32 = (const float*)Wv;
        for (int i = tid; i < KDIM; i += 256) Wl[i] = W32[(size_t)o * KDIM + i];
    }
    __syncthreads();
    const size_t pb = (size_t)b * CDIM * HW + (size_t)h * WI + tid;
    float acc = f ? __bfloat162float(((const __hip_bfloat16*)bv)[o]) : ((const float*)bv)[o];
    if (f) {
        const __hip_bfloat16* x = (const __hip_bfloat16*)xv;
        for (int c = 0; c < CDIM; ++c) {
            const __hip_bfloat16* xp = x + pb + (size_t)c * HW;
            float ctr = __bfloat162float(xp[0]);
            float rgt = (tid < 255) ? __bfloat162float(xp[1])   : 0.f;
            float lft = (tid > 0)   ? __bfloat162float(xp[-1])  : 0.f;
            float dwn = (h < 255)   ? __bfloat162float(xp[WI])  : 0.f;
            float up  = (h > 0)     ? __bfloat162float(xp[-WI]) : 0.f;
            acc += ctr * Wl[c] + rgt * Wl[192 + c] + lft * Wl[384 + c]
                 + dwn * Wl[576 + c] + up * Wl[768 + c];
        }
    } else {
        const float* x = (const float*)xv;
        for (int c = 0; c < CDIM; ++c) {
            const float* xp = x + pb + (size_t)c * HW;
            float ctr = xp[0];
            float rgt = (tid < 255) ? xp[1]   : 0.f;
            float lft = (tid > 0)   ? xp[-1]  : 0.f;
            float dwn = (h < 255)   ? xp[WI]  : 0.f;
            float up  = (h > 0)     ? xp[-WI] : 0.f;
            acc += ctr * Wl[c] + rgt * Wl[192 + c] + lft * Wl[384 + c]
                 + dwn * Wl[576 + c] + up * Wl[768 + c];
        }
    }
    size_t oidx = (size_t)bo * HW + (size_t)h * WI + tid;
    if (f) ((__hip_bfloat16*)outv)[oidx] = __float2bfloat16(acc);
    else   ((float*)outv)[oidx] = acc;
}

extern "C" void kernel_launch(void* const* d_in, const int* in_sizes, int n_in,
                              void* d_out, int out_size, void* d_ws, size_t ws_size,
                              hipStream_t stream) {
    (void)in_sizes; (void)n_in; (void)out_size;
    char* ws = (char*)d_ws;

    if (ws_size >= NEED_WS) {
        __hip_bfloat16* Wb = (__hip_bfloat16*)ws;
        float* bfp = (float*)(ws + OFF_BIAS);
        prep_kernel<<<721, 256, 0, stream>>>(d_in[1], d_in[2], d_in[0], Wb, bfp);
        fused_kernel<<<2048, 256, 0, stream>>>(d_in[0], Wb, bfp, d_out);
    } else {
        fallback_kernel<<<4 * CDIM * 256, 256, 0, stream>>>(d_in[0], d_in[1], d_in[2], d_out);
    }
}